// Round 8
// baseline (286.060 us; speedup 1.0000x reference)
//
#include <hip/hip_runtime.h>
#include <hip/hip_bf16.h>
#include <math.h>

#define B_ 8
#define S_ 1024
#define D_ 768
#define H_ 12
// DH = 64
#define QSCALE 0.18033688011112042f  // 0.125 * log2(e): softmax done base-2

typedef __attribute__((ext_vector_type(8))) short short8;
typedef __attribute__((ext_vector_type(4))) float floatx4;
typedef unsigned short ushort_t;

__device__ __forceinline__ ushort_t f2bf(float f) {  // RNE fp32 -> bf16
  unsigned int u = __builtin_bit_cast(unsigned int, f);
  u += 0x7fffu + ((u >> 16) & 1u);
  return (ushort_t)(u >> 16);
}

__device__ __forceinline__ unsigned int pkbf(float a, float b) {
  // packed RNE fp32x2 -> bf16x2 (v_cvt_pk_bf16_f32 on gfx950)
  __hip_bfloat162 h = __float22bfloat162_rn(make_float2(a, b));
  unsigned int r;
  __builtin_memcpy(&r, &h, sizeof(r));  // bit_cast rejects non-trivial type
  return r;
}

// Branch-free GELU (exact erf formulation, A&S 7.1.26, |eps_erf|<=1.5e-7).
__device__ __forceinline__ float gelu_f(float x) {
  const float z = fabsf(x) * 0.70710678118654752f;
  const float t = __builtin_amdgcn_rcpf(1.0f + 0.3275911f * z);
  const float p =
      t * (0.254829592f +
           t * (-0.284496736f +
                t * (1.421413741f + t * (-1.453152027f + t * 1.061405429f))));
  const float e = __expf(-z * z);
  const float erfv = 1.0f - p * e;  // erf(|x|/sqrt2)
  return 0.5f * x * (1.0f + copysignf(erfv, x));
}

template <int N>
__device__ __forceinline__ void wait_vmcnt() {
  if constexpr (N == 0)
    asm volatile("s_waitcnt vmcnt(0)" ::: "memory");
  else if constexpr (N == 3)
    asm volatile("s_waitcnt vmcnt(3)" ::: "memory");
  else if constexpr (N == 4)
    asm volatile("s_waitcnt vmcnt(4)" ::: "memory");
  else if constexpr (N == 6)
    asm volatile("s_waitcnt vmcnt(6)" ::: "memory");
  else
    asm volatile("s_waitcnt vmcnt(8)" ::: "memory");
}

// ------------- LayerNorm: one wave per row, shfl-only reduction -----------
__global__ __launch_bounds__(256) void ln_bf16(
    const float* __restrict__ in, const float* __restrict__ g,
    const float* __restrict__ bias, ushort_t* __restrict__ out) {
  const int row = blockIdx.x * 4 + (threadIdx.x >> 6);
  const int lane = threadIdx.x & 63;
  const float* p = in + (size_t)row * D_;
  float4 v[3];
#pragma unroll
  for (int j = 0; j < 3; ++j) v[j] = *(const float4*)(p + j * 256 + lane * 4);
  float s = 0.f;
#pragma unroll
  for (int j = 0; j < 3; ++j) s += (v[j].x + v[j].y) + (v[j].z + v[j].w);
#pragma unroll
  for (int m = 1; m < 64; m <<= 1) s += __shfl_xor(s, m);
  const float mean = s * (1.0f / D_);
  float q = 0.f;
#pragma unroll
  for (int j = 0; j < 3; ++j) {
    const float a = v[j].x - mean, b = v[j].y - mean;
    const float c = v[j].z - mean, d = v[j].w - mean;
    q += (a * a + b * b) + (c * c + d * d);
  }
#pragma unroll
  for (int m = 1; m < 64; m <<= 1) q += __shfl_xor(q, m);
  const float rstd = rsqrtf(q * (1.0f / D_) + 1e-5f);
  ushort_t* o = out + (size_t)row * D_;
#pragma unroll
  for (int j = 0; j < 3; ++j) {
    const float4 gv = *(const float4*)(g + j * 256 + lane * 4);
    const float4 bv = *(const float4*)(bias + j * 256 + lane * 4);
    const unsigned int p01 = pkbf((v[j].x - mean) * rstd * gv.x + bv.x,
                                  (v[j].y - mean) * rstd * gv.y + bv.y);
    const unsigned int p23 = pkbf((v[j].z - mean) * rstd * gv.z + bv.z,
                                  (v[j].w - mean) * rstd * gv.w + bv.w);
    *(uint2*)(o + j * 256 + lane * 4) = make_uint2(p01, p23);
  }
}

// ---------------- transpose + cast: W (K x N fp32) -> Wt (N x K bf16) -----
__global__ __launch_bounds__(256) void transpose_cast(
    const float* __restrict__ W, ushort_t* __restrict__ Wt, int Kdim, int Ndim) {
  __shared__ float tile[32][33];
  const int n0 = blockIdx.x * 32, k0 = blockIdx.y * 32;
  const int tx = threadIdx.x & 31, ty = threadIdx.x >> 5;  // ty 0..7
#pragma unroll
  for (int i = 0; i < 32; i += 8)
    tile[ty + i][tx] = W[(size_t)(k0 + ty + i) * Ndim + n0 + tx];
  __syncthreads();
#pragma unroll
  for (int i = 0; i < 32; i += 8)
    Wt[(size_t)(n0 + ty + i) * Kdim + k0 + tx] = f2bf(tile[tx][ty + i]);
}

// -------- per-head 64x64 weight transpose+cast (Wq/Wk/Wv -> e-major bf16) --
__global__ __launch_bounds__(256) void trans_w64(
    const float* __restrict__ Wq, const float* __restrict__ Wk,
    const float* __restrict__ Wv, ushort_t* __restrict__ Wqt,
    ushort_t* __restrict__ Wkt, ushort_t* __restrict__ Wvt) {
  const int h = blockIdx.x;
  const float* W = blockIdx.y == 0 ? Wq : blockIdx.y == 1 ? Wk : Wv;
  ushort_t* O = blockIdx.y == 0 ? Wqt : blockIdx.y == 1 ? Wkt : Wvt;
  __shared__ float t[64][65];
  const int tid = threadIdx.x;
#pragma unroll
  for (int i = 0; i < 16; ++i) {
    const int idx = tid + i * 256;
    t[idx >> 6][idx & 63] = W[h * 4096 + idx];
  }
  __syncthreads();
#pragma unroll
  for (int i = 0; i < 16; ++i) {
    const int idx = tid + i * 256;
    O[h * 4096 + idx] = f2bf(t[idx & 63][idx >> 6]);  // O[e][d] = W[d][e]
  }
}

// -------- QKV projection, bf16 MFMA; coalesced stores via wave-private LDS -
// (r7 structure, measured-good: Q,K via swapped mfma(W,x) -> LDS bounce ->
// 128-B row stores; V -> LDS -> 64-B segment stores of V^T.)
__global__ __launch_bounds__(256) void qkv_mfma(
    const ushort_t* __restrict__ xbf,
    const ushort_t* __restrict__ Wqt, const ushort_t* __restrict__ Wkt,
    const ushort_t* __restrict__ Wvt,
    const float* __restrict__ bq, const float* __restrict__ bk,
    const float* __restrict__ bv,
    ushort_t* __restrict__ qo, ushort_t* __restrict__ ko,
    ushort_t* __restrict__ vt) {
  const int h = blockIdx.y;
  const int mb = blockIdx.x * 128;
  const int tid = threadIdx.x;
  const int wave = tid >> 6, lane = tid & 63;
  const int lc = lane & 15, kq = lane >> 4;
  const int wm = wave * 32;

  // per-wave bounce buffer: max(32x72, 64x40) ush = 2560 ush = 5120 B
  __shared__ __align__(16) ushort_t Lb[4][2560];
  ushort_t* Lw = Lb[wave];

  short8 af[2][2];
#pragma unroll
  for (int mi = 0; mi < 2; ++mi)
#pragma unroll
    for (int kc = 0; kc < 2; ++kc)
      af[mi][kc] = *(const short8*)(xbf + (size_t)(mb + wm + mi * 16 + lc) * D_ +
                                    h * 64 + kc * 32 + kq * 8);

  const ushort_t* Wp[3] = {Wqt + h * 4096, Wkt + h * 4096, Wvt + h * 4096};
  floatx4 accT[2][2][4] = {};  // Q,K swapped: [w3][mi][n], lane: s=mi*16+lc
  floatx4 accV[2][4] = {};     // V: [mi][n], lane: e=n*16+lc
#pragma unroll
  for (int n = 0; n < 4; ++n)
#pragma unroll
    for (int kc = 0; kc < 2; ++kc) {
      const short8 wq_ = *(const short8*)(Wp[0] + (n * 16 + lc) * 64 +
                                          kc * 32 + kq * 8);
      const short8 wk_ = *(const short8*)(Wp[1] + (n * 16 + lc) * 64 +
                                          kc * 32 + kq * 8);
      const short8 wv_ = *(const short8*)(Wp[2] + (n * 16 + lc) * 64 +
                                          kc * 32 + kq * 8);
#pragma unroll
      for (int mi = 0; mi < 2; ++mi) {
        accT[0][mi][n] = __builtin_amdgcn_mfma_f32_16x16x32_bf16(
            wq_, af[mi][kc], accT[0][mi][n], 0, 0, 0);
        accT[1][mi][n] = __builtin_amdgcn_mfma_f32_16x16x32_bf16(
            wk_, af[mi][kc], accT[1][mi][n], 0, 0, 0);
        accV[mi][n] = __builtin_amdgcn_mfma_f32_16x16x32_bf16(
            af[mi][kc], wv_, accV[mi][n], 0, 0, 0);
      }
    }

  const int b = mb >> 10;
  const size_t obase = (size_t)(b * H_ + h) * (S_ * 64);
  const int sbase = (mb & 1023) + wm;

  // ---- Q then K: accT lane holds (s = mi*16+lc, e = n*16+kq*4 + r) ----
#pragma unroll
  for (int w3 = 0; w3 < 2; ++w3) {
    const float* bias = (w3 == 0 ? bq : bk) + h * 64;
    ushort_t* outp = w3 == 0 ? qo : ko;
#pragma unroll
    for (int mi = 0; mi < 2; ++mi)
#pragma unroll
      for (int n = 0; n < 4; ++n) {
        const float4 bv4 = *(const float4*)(bias + n * 16 + kq * 4);
        const floatx4 v = accT[w3][mi][n];
        float v0 = v[0] + bv4.x, v1 = v[1] + bv4.y;
        float v2 = v[2] + bv4.z, v3 = v[3] + bv4.w;
        if (w3 == 0) { v0 *= QSCALE; v1 *= QSCALE; v2 *= QSCALE; v3 *= QSCALE; }
        *(uint2*)(&Lw[(mi * 16 + lc) * 72 + n * 16 + kq * 4]) =
            make_uint2(pkbf(v0, v1), pkbf(v2, v3));
      }
    asm volatile("s_waitcnt lgkmcnt(0)" ::: "memory");
    const int srow = lane >> 2, c16 = (lane & 3) * 16;
#pragma unroll
    for (int it = 0; it < 2; ++it) {
      const int s = it * 16 + srow;
      const uint4 r0 = *(const uint4*)(&Lw[s * 72 + c16]);
      const uint4 r1 = *(const uint4*)(&Lw[s * 72 + c16 + 8]);
      *(uint4*)(outp + obase + (size_t)(sbase + s) * 64 + c16) = r0;
      *(uint4*)(outp + obase + (size_t)(sbase + s) * 64 + c16 + 8) = r1;
    }
    asm volatile("s_waitcnt lgkmcnt(0)" ::: "memory");  // reads done, reuse Lw
  }

  // ---- V: accV lane holds (e = n*16+lc, s = mi*16+kq*4 + r) ----
#pragma unroll
  for (int n = 0; n < 4; ++n) {
    const float bvv = bv[h * 64 + n * 16 + lc];
#pragma unroll
    for (int mi = 0; mi < 2; ++mi) {
      const floatx4 v = accV[mi][n];
      *(uint2*)(&Lw[(n * 16 + lc) * 40 + mi * 16 + kq * 4]) =
          make_uint2(pkbf(v[0] + bvv, v[1] + bvv),
                     pkbf(v[2] + bvv, v[3] + bvv));
    }
  }
  asm volatile("s_waitcnt lgkmcnt(0)" ::: "memory");
  {
    const int erow = lane >> 2, s8 = (lane & 3) * 8;
#pragma unroll
    for (int it = 0; it < 4; ++it) {
      const int e = it * 16 + erow;
      const uint4 r0 = *(const uint4*)(&Lw[e * 40 + s8]);
      *(uint4*)(vt + obase + (size_t)e * S_ + sbase + s8) = r0;
    }
  }
}

// ------- flash attention: 8 waves x 16 q, K/V LDS-staged + XOR-swizzled ----
// (r3/r5 structure, unchanged)
__global__ __launch_bounds__(512) void attn_mfma(
    const ushort_t* __restrict__ qb, const ushort_t* __restrict__ kb,
    const ushort_t* __restrict__ vt, const float* __restrict__ x,
    float* __restrict__ out1) {
  const int bh = blockIdx.x;
  const int tid = threadIdx.x;
  const int wave = tid >> 6, lane = tid & 63;  // wave 0..7
  const int lc = lane & 15, kq = lane >> 4;
  const int q0 = blockIdx.y * 128 + wave * 16;

  __shared__ __align__(16) ushort_t smem[8192 + 8 * 16 * 72];  // 34816 B
  ushort_t* Ks = smem;                       // [key][d], chunk-swizzled
  ushort_t* Vs = smem + 4096;                // [d][s],  chunk-swizzled
  ushort_t* Pp = smem + 8192 + wave * (16 * 72);

  const ushort_t* qp = qb + (size_t)bh * (S_ * 64);
  const ushort_t* kp = kb + (size_t)bh * (S_ * 64);
  const ushort_t* vp = vt + (size_t)bh * (S_ * 64);

  short8 qf[2];
#pragma unroll
  for (int kc = 0; kc < 2; ++kc)
    qf[kc] = *(const short8*)(qp + (size_t)(q0 + lc) * 64 + kc * 32 + kq * 8);

  const int srow = tid >> 3;                             // 0..63
  const int sgc = ((tid & 7) ^ (srow & 7)) * 8;          // global col (elems)
  const int slds = srow * 64 + (tid & 7) * 8;            // LDS offset (elems)
  const int swz = lc & 7;                                // frag-read swizzle

  float l_r = 0.0f;
  floatx4 oacc[4] = {};  // [d-tile]

  for (int kt = 0; kt < 16; ++kt) {
    __builtin_amdgcn_global_load_lds(
        (const __attribute__((address_space(1))) unsigned int*)
            (kp + (size_t)(kt * 64 + srow) * 64 + sgc),
        (__attribute__((address_space(3))) unsigned int*)(Ks + slds), 16, 0, 0);
    __builtin_amdgcn_global_load_lds(
        (const __attribute__((address_space(1))) unsigned int*)
            (vp + (size_t)srow * S_ + kt * 64 + sgc),
        (__attribute__((address_space(3))) unsigned int*)(Vs + slds), 16, 0, 0);
    __syncthreads();

    // ---- QK: S^T tile, 16 q-rows per wave ----
    floatx4 sacc[4] = {};
#pragma unroll
    for (int mi = 0; mi < 4; ++mi) {
      const int row = (mi * 16 + lc) * 64;
#pragma unroll
      for (int kc = 0; kc < 2; ++kc) {
        const short8 kf =
            *(const short8*)(Ks + row + ((kc * 4 + kq) ^ swz) * 8);
        sacc[mi] = __builtin_amdgcn_mfma_f32_16x16x32_bf16(
            kf, qf[kc], sacc[mi], 0, 0, 0);
      }
    }

    // ---- softmax numerator (no max subtraction) ----
    float pr[4][4];
    float sm = 0.f;
#pragma unroll
    for (int mi = 0; mi < 4; ++mi)
#pragma unroll
      for (int r = 0; r < 4; ++r) {
        pr[mi][r] = exp2f(sacc[mi][r]);
        sm += pr[mi][r];
      }
    l_r += sm;  // per-lane partial; reduced at epilogue
#pragma unroll
    for (int mi = 0; mi < 4; ++mi) {
      const unsigned int p01 = pkbf(pr[mi][0], pr[mi][1]);
      const unsigned int p23 = pkbf(pr[mi][2], pr[mi][3]);
      *(uint2*)(&Pp[lc * 72 + mi * 16 + kq * 4]) = make_uint2(p01, p23);
    }
    asm volatile("s_waitcnt lgkmcnt(0)" ::: "memory");

    // ---- PV: O^T += V^T * P^T ----
    short8 pf[2];
#pragma unroll
    for (int kc = 0; kc < 2; ++kc)
      pf[kc] = *(const short8*)(&Pp[lc * 72 + kc * 32 + kq * 8]);
#pragma unroll
    for (int mi = 0; mi < 4; ++mi) {
      const int row = (mi * 16 + lc) * 64;
#pragma unroll
      for (int kc = 0; kc < 2; ++kc) {
        const short8 vf =
            *(const short8*)(Vs + row + ((kc * 4 + kq) ^ swz) * 8);
        oacc[mi] = __builtin_amdgcn_mfma_f32_16x16x32_bf16(
            vf, pf[kc], oacc[mi], 0, 0, 0);
      }
    }
    __syncthreads();  // Ks/Vs/Pp reads done before next stage overwrites
  }

  // ---- epilogue: finalize l, O^T -> LDS -> dense 128-B stores + resid ----
  const int b = bh / H_, h = bh % H_;
  float lt = l_r;
  lt += __shfl_xor(lt, 16);
  lt += __shfl_xor(lt, 32);
  const float inv = 1.0f / lt;
  float* Ow = (float*)smem + wave * 1088;
#pragma unroll
  for (int mi = 0; mi < 4; ++mi) {
    floatx4 ov = oacc[mi];
    ov[0] *= inv; ov[1] *= inv; ov[2] *= inv; ov[3] *= inv;
    *(floatx4*)(&Ow[lc * 68 + mi * 16 + kq * 4]) = ov;
  }
  asm volatile("s_waitcnt lgkmcnt(0)" ::: "memory");
  const int row = (lane >> 3) & 7, c8 = (lane & 7) * 4;
#pragma unroll
  for (int rg = 0; rg < 2; ++rg) {
    const int qq = rg * 8 + row;
    const size_t gbase =
        ((size_t)(b * S_) + q0 + qq) * D_ + h * 64 + c8;
#pragma unroll
    for (int j = 0; j < 2; ++j) {
      const float4 ov = *(const float4*)(&Ow[qq * 68 + j * 32 + c8]);
      const float4 xv = *(const float4*)(x + gbase + j * 32);
      *(float4*)(out1 + gbase + j * 32) =
          make_float4(ov.x + xv.x, ov.y + xv.y, ov.z + xv.z, ov.w + xv.w);
    }
  }
}

// ======== pipelined bf16 MFMA GEMM (r5 structure, verbatim) ========
// 512 threads / 8 waves (2M x 4N), wave tile (BM/2)x(BN/4); BK=64 LDS dbuf;
// counted vmcnt keeps tile t+2's loads in flight across both barriers.
// XCDMAP measured-good ONLY for GEMM2's shape (N=768); for GEMM1 (N=3072)
// it RAISED FETCH_SIZE 57.6->70MB and cost 16us (r7) -> 2D grid there.
template <int BM, int BN, int N, int K, bool GELU, bool RESID, bool OUT_BF16,
          bool XCDMAP>
__global__ __launch_bounds__(512, 4) void gemm_pipe(
    const ushort_t* __restrict__ A, const ushort_t* __restrict__ Bt,
    const float* __restrict__ resid, void* __restrict__ Cout) {
  constexpr int MI = BM / 32;             // m-frags per wave
  constexpr int NJ = BN / 64;             // n-frags per wave
  constexpr int LPT = BM / 64 + BN / 64;  // gload_lds per thread per K-tile
  constexpr int NT = K / 64;

  int mb, nb;
  if constexpr (XCDMAP) {
    const int lin = blockIdx.x;
    const int xcd = lin & 7, slot = lin >> 3;
    const int mbg = slot / (N / 128), nbi = slot - mbg * (N / 128);
    mb = (xcd * 16 + mbg) * 64;
    nb = nbi * 128;
  } else {
    nb = blockIdx.x * BN;
    mb = blockIdx.y * BM;
  }

  const int tid = threadIdx.x;
  const int wave = tid >> 6, lane = tid & 63;  // wave 0..7
  const int wm = (wave >> 2) * (BM / 2), wn = (wave & 3) * (BN / 4);

  __shared__ __align__(16) ushort_t Asp[2][BM * 64];
  __shared__ __align__(16) ushort_t Bsp[2][BN * 64];

  // staging geometry: 64 rows x 8 chunks of 16B per issue group
  const int sr = tid >> 3;                      // 0..63
  const int sc8 = (tid & 7) * 8;                // LDS chunk (lane-linear dest)
  const int sgx = ((tid & 7) ^ (sr & 7)) * 8;   // pre-swizzled global chunk

  auto stage = [&](int t, int buf) {
    const int kb = t * 64;
#pragma unroll
    for (int j = 0; j < BM / 64; ++j) {
      const int row = j * 64 + sr;
      __builtin_amdgcn_global_load_lds(
          (const __attribute__((address_space(1))) unsigned int*)
              (A + (size_t)(mb + row) * K + kb + sgx),
          (__attribute__((address_space(3))) unsigned int*)
              (&Asp[buf][row * 64 + sc8]), 16, 0, 0);
    }
#pragma unroll
    for (int j = 0; j < BN / 64; ++j) {
      const int row = j * 64 + sr;
      __builtin_amdgcn_global_load_lds(
          (const __attribute__((address_space(1))) unsigned int*)
              (Bt + (size_t)(nb + row) * K + kb + sgx),
          (__attribute__((address_space(3))) unsigned int*)
              (&Bsp[buf][row * 64 + sc8]), 16, 0, 0);
    }
  };

  // prologue: tiles 0 and 1 in flight; wait for tile 0 only
  stage(0, 0);
  stage(1, 1);
  wait_vmcnt<LPT>();
  __builtin_amdgcn_s_barrier();
  __builtin_amdgcn_sched_barrier(0);

  const int lc = lane & 15, kq = lane >> 4, swz = lc & 7;
  floatx4 acc[MI][NJ] = {};

#pragma unroll 1
  for (int t = 0; t < NT; ++t) {
    const int cur = t & 1;
    short8 af[MI][2], bfr[NJ][2];
#pragma unroll
    for (int i = 0; i < MI; ++i)
#pragma unroll
      for (int ks = 0; ks < 2; ++ks)
        af[i][ks] = *(const short8*)(&Asp[cur][(wm + i * 16 + lc) * 64 +
                                               ((ks * 4 + kq) ^ swz) * 8]);
#pragma unroll
    for (int j = 0; j < NJ; ++j)
#pragma unroll
      for (int ks = 0; ks < 2; ++ks)
        bfr[j][ks] = *(const short8*)(&Bsp[cur][(wn + j * 16 + lc) * 64 +
                                                ((ks * 4 + kq) ^ swz) * 8]);
    asm volatile("s_waitcnt lgkmcnt(0)" ::: "memory");
    __builtin_amdgcn_sched_barrier(0);
    __builtin_amdgcn_s_barrier();  // #1: all waves' frag reads complete
    __builtin_amdgcn_sched_barrier(0);
    if (t + 2 < NT) stage(t + 2, cur);  // overwrite just-freed buffer
    __builtin_amdgcn_sched_barrier(0);
    __builtin_amdgcn_s_setprio(1);
#pragma unroll
    for (int ks = 0; ks < 2; ++ks)
#pragma unroll
      for (int i = 0; i < MI; ++i)
#pragma unroll
        for (int j = 0; j < NJ; ++j)
          acc[i][j] = __builtin_amdgcn_mfma_f32_16x16x32_bf16(
              af[i][ks], bfr[j][ks], acc[i][j], 0, 0, 0);
    __builtin_amdgcn_s_setprio(0);
    if (t + 2 < NT)
      wait_vmcnt<LPT>();  // tile t+1 landed; t+2's LPT stay in flight
    else if (t + 1 < NT)
      wait_vmcnt<0>();    // tail: nothing behind tile t+1
    if (t + 1 < NT) {
      __builtin_amdgcn_s_barrier();  // #2: tile t+1 resident on every wave
      __builtin_amdgcn_sched_barrier(0);
    }
  }

  const int lcol = lane & 15, lr4 = (lane >> 4) * 4;
#pragma unroll
  for (int i = 0; i < MI; ++i)
#pragma unroll
    for (int r = 0; r < 4; ++r) {
      const int m = mb + wm + i * 16 + lr4 + r;
#pragma unroll
      for (int j = 0; j < NJ; ++j) {
        const int col = nb + wn + j * 16 + lcol;
        float vv = acc[i][j][r];
        if (GELU) vv = gelu_f(vv);
        if (RESID) vv += resid[(size_t)m * N + col];
        if (OUT_BF16)
          ((ushort_t*)Cout)[(size_t)m * N + col] = f2bf(vv);
        else
          ((float*)Cout)[(size_t)m * N + col] = vv;
      }
    }
}

extern "C" void kernel_launch(void* const* d_in, const int* in_sizes, int n_in,
                              void* d_out, int out_size, void* d_ws, size_t ws_size,
                              hipStream_t stream) {
  (void)in_sizes; (void)n_in; (void)out_size; (void)ws_size;
  const float* x     = (const float*)d_in[0];
  const float* ln1_g = (const float*)d_in[1];
  const float* ln1_b = (const float*)d_in[2];
  const float* Wq    = (const float*)d_in[3];
  const float* bq    = (const float*)d_in[4];
  const float* Wk    = (const float*)d_in[5];
  const float* bk    = (const float*)d_in[6];
  const float* Wv    = (const float*)d_in[7];
  const float* bv    = (const float*)d_in[8];
  const float* ln2_g = (const float*)d_in[9];
  const float* ln2_b = (const float*)d_in[10];
  const float* W1    = (const float*)d_in[11];
  const float* W2    = (const float*)d_in[12];
  float* out = (float*)d_out;

  const size_t n = (size_t)B_ * S_ * D_;  // 6,291,456
  ushort_t* u = (ushort_t*)d_ws;
  ushort_t* xbf  = u;                 // LN1 out bf16
  ushort_t* qb   = xbf + n;           // [96][1024][64]
  ushort_t* kb   = qb + n;
  ushort_t* vt   = kb + n;            // [96][64][1024]  (written by qkv)
  ushort_t* xbf2 = vt + n;            // LN2 out bf16
  ushort_t* act  = xbf2 + n;          // 8192 x 3072
  ushort_t* Wt1  = act + (size_t)8192 * 3072;
  ushort_t* Wt2  = Wt1 + (size_t)3072 * 768;
  ushort_t* Wqt  = Wt2 + (size_t)768 * 3072;
  ushort_t* Wkt  = Wqt + H_ * 4096;
  ushort_t* Wvt  = Wkt + H_ * 4096;
  float* out1 = (float*)(Wvt + H_ * 4096);  // x + attn (fp32), n floats

  trans_w64<<<dim3(12, 3), dim3(256), 0, stream>>>(Wq, Wk, Wv, Wqt, Wkt, Wvt);
  transpose_cast<<<dim3(96, 24), dim3(256), 0, stream>>>(W1, Wt1, 768, 3072);
  transpose_cast<<<dim3(24, 96), dim3(256), 0, stream>>>(W2, Wt2, 3072, 768);
  ln_bf16<<<dim3(2048), dim3(256), 0, stream>>>(x, ln1_g, ln1_b, xbf);
  qkv_mfma<<<dim3(64, 12), dim3(256), 0, stream>>>(xbf, Wqt, Wkt, Wvt,
                                                   bq, bk, bv, qb, kb, vt);
  attn_mfma<<<dim3(96, 8), dim3(512), 0, stream>>>(qb, kb, vt, x, out1);
  ln_bf16<<<dim3(2048), dim3(256), 0, stream>>>(out1, ln2_g, ln2_b, xbf2);
  // FFN GEMM1: 8192x3072x768, GELU, bf16 out (128x128, 8 waves, 2D grid)
  gemm_pipe<128, 128, 3072, 768, true, false, true, false>
      <<<dim3(24, 64), dim3(512), 0, stream>>>(xbf2, Wt1, nullptr, act);
  // FFN GEMM2: 8192x768x3072, +resid, fp32 out (64x128, 8 waves, XCD-grouped)
  gemm_pipe<64, 128, 768, 3072, false, true, false, true>
      <<<dim3(768), dim3(512), 0, stream>>>(act, Wt2, out1, out);
}

// Round 9
// 277.692 us; speedup vs baseline: 1.0301x; 1.0301x over previous
//
#include <hip/hip_runtime.h>
#include <hip/hip_bf16.h>
#include <math.h>

#define B_ 8
#define S_ 1024
#define D_ 768
#define H_ 12
// DH = 64
#define QSCALE 0.18033688011112042f  // 0.125 * log2(e): softmax done base-2

typedef __attribute__((ext_vector_type(8))) short short8;
typedef __attribute__((ext_vector_type(4))) float floatx4;
typedef unsigned short ushort_t;

__device__ __forceinline__ ushort_t f2bf(float f) {  // RNE fp32 -> bf16
  unsigned int u = __builtin_bit_cast(unsigned int, f);
  u += 0x7fffu + ((u >> 16) & 1u);
  return (ushort_t)(u >> 16);
}

__device__ __forceinline__ unsigned int pkbf(float a, float b) {
  // packed RNE fp32x2 -> bf16x2 (v_cvt_pk_bf16_f32 on gfx950)
  __hip_bfloat162 h = __float22bfloat162_rn(make_float2(a, b));
  unsigned int r;
  __builtin_memcpy(&r, &h, sizeof(r));  // bit_cast rejects non-trivial type
  return r;
}

// Branch-free GELU (exact erf formulation, A&S 7.1.26, |eps_erf|<=1.5e-7).
__device__ __forceinline__ float gelu_f(float x) {
  const float z = fabsf(x) * 0.70710678118654752f;
  const float t = __builtin_amdgcn_rcpf(1.0f + 0.3275911f * z);
  const float p =
      t * (0.254829592f +
           t * (-0.284496736f +
                t * (1.421413741f + t * (-1.453152027f + t * 1.061405429f))));
  const float e = __expf(-z * z);
  const float erfv = 1.0f - p * e;  // erf(|x|/sqrt2)
  return 0.5f * x * (1.0f + copysignf(erfv, x));
}

template <int N>
__device__ __forceinline__ void wait_vmcnt() {
  if constexpr (N == 0)
    asm volatile("s_waitcnt vmcnt(0)" ::: "memory");
  else if constexpr (N == 3)
    asm volatile("s_waitcnt vmcnt(3)" ::: "memory");
  else if constexpr (N == 4)
    asm volatile("s_waitcnt vmcnt(4)" ::: "memory");
  else if constexpr (N == 6)
    asm volatile("s_waitcnt vmcnt(6)" ::: "memory");
  else
    asm volatile("s_waitcnt vmcnt(8)" ::: "memory");
}

// ------------- LayerNorm: one wave per row, shfl-only reduction -----------
__global__ __launch_bounds__(256) void ln_bf16(
    const float* __restrict__ in, const float* __restrict__ g,
    const float* __restrict__ bias, ushort_t* __restrict__ out) {
  const int row = blockIdx.x * 4 + (threadIdx.x >> 6);
  const int lane = threadIdx.x & 63;
  const float* p = in + (size_t)row * D_;
  float4 v[3];
#pragma unroll
  for (int j = 0; j < 3; ++j) v[j] = *(const float4*)(p + j * 256 + lane * 4);
  float s = 0.f;
#pragma unroll
  for (int j = 0; j < 3; ++j) s += (v[j].x + v[j].y) + (v[j].z + v[j].w);
#pragma unroll
  for (int m = 1; m < 64; m <<= 1) s += __shfl_xor(s, m);
  const float mean = s * (1.0f / D_);
  float q = 0.f;
#pragma unroll
  for (int j = 0; j < 3; ++j) {
    const float a = v[j].x - mean, b = v[j].y - mean;
    const float c = v[j].z - mean, d = v[j].w - mean;
    q += (a * a + b * b) + (c * c + d * d);
  }
#pragma unroll
  for (int m = 1; m < 64; m <<= 1) q += __shfl_xor(q, m);
  const float rstd = rsqrtf(q * (1.0f / D_) + 1e-5f);
  ushort_t* o = out + (size_t)row * D_;
#pragma unroll
  for (int j = 0; j < 3; ++j) {
    const float4 gv = *(const float4*)(g + j * 256 + lane * 4);
    const float4 bv = *(const float4*)(bias + j * 256 + lane * 4);
    const unsigned int p01 = pkbf((v[j].x - mean) * rstd * gv.x + bv.x,
                                  (v[j].y - mean) * rstd * gv.y + bv.y);
    const unsigned int p23 = pkbf((v[j].z - mean) * rstd * gv.z + bv.z,
                                  (v[j].w - mean) * rstd * gv.w + bv.w);
    *(uint2*)(o + j * 256 + lane * 4) = make_uint2(p01, p23);
  }
}

// --------- fused weight prep: W1^T, W2^T (32x32 tiles) + per-head 64x64 ----
// One launch instead of three (launch-gap reduction; bodies are the proven
// transpose_cast / trans_w64 kernels verbatim, sharing one LDS pool).
__device__ __forceinline__ void tcast_body(
    const float* __restrict__ W, ushort_t* __restrict__ Wt,
    int Kdim, int Ndim, int bx, int by, float* sh) {
  float(*tile)[33] = (float(*)[33])sh;
  const int n0 = bx * 32, k0 = by * 32;
  const int tx = threadIdx.x & 31, ty = threadIdx.x >> 5;  // ty 0..7
#pragma unroll
  for (int i = 0; i < 32; i += 8)
    tile[ty + i][tx] = W[(size_t)(k0 + ty + i) * Ndim + n0 + tx];
  __syncthreads();
#pragma unroll
  for (int i = 0; i < 32; i += 8)
    Wt[(size_t)(n0 + ty + i) * Kdim + k0 + tx] = f2bf(tile[tx][ty + i]);
}

__global__ __launch_bounds__(256) void prep_weights(
    const float* __restrict__ W1, ushort_t* __restrict__ Wt1,
    const float* __restrict__ W2, ushort_t* __restrict__ Wt2,
    const float* __restrict__ Wq, const float* __restrict__ Wk,
    const float* __restrict__ Wv, ushort_t* __restrict__ Wqt,
    ushort_t* __restrict__ Wkt, ushort_t* __restrict__ Wvt) {
  __shared__ float sh[64 * 65];
  const int bid = blockIdx.x;
  if (bid < 2304) {  // W1: K=768(24 tiles) x N=3072(96 tiles)
    tcast_body(W1, Wt1, 768, 3072, bid % 96, bid / 96, sh);
  } else if (bid < 4608) {  // W2: K=3072(96) x N=768(24)
    const int idx = bid - 2304;
    tcast_body(W2, Wt2, 3072, 768, idx % 24, idx / 24, sh);
  } else {  // 36 blocks: per-head 64x64 transpose of Wq/Wk/Wv
    const int idx = bid - 4608;
    const int h = idx % 12, which = idx / 12;
    const float* W = which == 0 ? Wq : which == 1 ? Wk : Wv;
    ushort_t* O = which == 0 ? Wqt : which == 1 ? Wkt : Wvt;
    float(*t)[65] = (float(*)[65])sh;
    const int tid = threadIdx.x;
#pragma unroll
    for (int i = 0; i < 16; ++i) {
      const int idx2 = tid + i * 256;
      t[idx2 >> 6][idx2 & 63] = W[h * 4096 + idx2];
    }
    __syncthreads();
#pragma unroll
    for (int i = 0; i < 16; ++i) {
      const int idx2 = tid + i * 256;
      O[h * 4096 + idx2] = f2bf(t[idx2 & 63][idx2 >> 6]);  // O[e][d]=W[d][e]
    }
  }
}

// -------- QKV projection, bf16 MFMA; coalesced stores via wave-private LDS -
// (r7 structure, measured-good: Q,K via swapped mfma(W,x) -> LDS bounce ->
// 128-B row stores; V -> LDS -> 64-B segment stores of V^T.)
__global__ __launch_bounds__(256) void qkv_mfma(
    const ushort_t* __restrict__ xbf,
    const ushort_t* __restrict__ Wqt, const ushort_t* __restrict__ Wkt,
    const ushort_t* __restrict__ Wvt,
    const float* __restrict__ bq, const float* __restrict__ bk,
    const float* __restrict__ bv,
    ushort_t* __restrict__ qo, ushort_t* __restrict__ ko,
    ushort_t* __restrict__ vt) {
  const int h = blockIdx.y;
  const int mb = blockIdx.x * 128;
  const int tid = threadIdx.x;
  const int wave = tid >> 6, lane = tid & 63;
  const int lc = lane & 15, kq = lane >> 4;
  const int wm = wave * 32;

  // per-wave bounce buffer: max(32x72, 64x40) ush = 2560 ush = 5120 B
  __shared__ __align__(16) ushort_t Lb[4][2560];
  ushort_t* Lw = Lb[wave];

  short8 af[2][2];
#pragma unroll
  for (int mi = 0; mi < 2; ++mi)
#pragma unroll
    for (int kc = 0; kc < 2; ++kc)
      af[mi][kc] = *(const short8*)(xbf + (size_t)(mb + wm + mi * 16 + lc) * D_ +
                                    h * 64 + kc * 32 + kq * 8);

  const ushort_t* Wp[3] = {Wqt + h * 4096, Wkt + h * 4096, Wvt + h * 4096};
  floatx4 accT[2][2][4] = {};  // Q,K swapped: [w3][mi][n], lane: s=mi*16+lc
  floatx4 accV[2][4] = {};     // V: [mi][n], lane: e=n*16+lc
#pragma unroll
  for (int n = 0; n < 4; ++n)
#pragma unroll
    for (int kc = 0; kc < 2; ++kc) {
      const short8 wq_ = *(const short8*)(Wp[0] + (n * 16 + lc) * 64 +
                                          kc * 32 + kq * 8);
      const short8 wk_ = *(const short8*)(Wp[1] + (n * 16 + lc) * 64 +
                                          kc * 32 + kq * 8);
      const short8 wv_ = *(const short8*)(Wp[2] + (n * 16 + lc) * 64 +
                                          kc * 32 + kq * 8);
#pragma unroll
      for (int mi = 0; mi < 2; ++mi) {
        accT[0][mi][n] = __builtin_amdgcn_mfma_f32_16x16x32_bf16(
            wq_, af[mi][kc], accT[0][mi][n], 0, 0, 0);
        accT[1][mi][n] = __builtin_amdgcn_mfma_f32_16x16x32_bf16(
            wk_, af[mi][kc], accT[1][mi][n], 0, 0, 0);
        accV[mi][n] = __builtin_amdgcn_mfma_f32_16x16x32_bf16(
            af[mi][kc], wv_, accV[mi][n], 0, 0, 0);
      }
    }

  const int b = mb >> 10;
  const size_t obase = (size_t)(b * H_ + h) * (S_ * 64);
  const int sbase = (mb & 1023) + wm;

  // ---- Q then K: accT lane holds (s = mi*16+lc, e = n*16+kq*4 + r) ----
#pragma unroll
  for (int w3 = 0; w3 < 2; ++w3) {
    const float* bias = (w3 == 0 ? bq : bk) + h * 64;
    ushort_t* outp = w3 == 0 ? qo : ko;
#pragma unroll
    for (int mi = 0; mi < 2; ++mi)
#pragma unroll
      for (int n = 0; n < 4; ++n) {
        const float4 bv4 = *(const float4*)(bias + n * 16 + kq * 4);
        const floatx4 v = accT[w3][mi][n];
        float v0 = v[0] + bv4.x, v1 = v[1] + bv4.y;
        float v2 = v[2] + bv4.z, v3 = v[3] + bv4.w;
        if (w3 == 0) { v0 *= QSCALE; v1 *= QSCALE; v2 *= QSCALE; v3 *= QSCALE; }
        *(uint2*)(&Lw[(mi * 16 + lc) * 72 + n * 16 + kq * 4]) =
            make_uint2(pkbf(v0, v1), pkbf(v2, v3));
      }
    asm volatile("s_waitcnt lgkmcnt(0)" ::: "memory");
    const int srow = lane >> 2, c16 = (lane & 3) * 16;
#pragma unroll
    for (int it = 0; it < 2; ++it) {
      const int s = it * 16 + srow;
      const uint4 r0 = *(const uint4*)(&Lw[s * 72 + c16]);
      const uint4 r1 = *(const uint4*)(&Lw[s * 72 + c16 + 8]);
      *(uint4*)(outp + obase + (size_t)(sbase + s) * 64 + c16) = r0;
      *(uint4*)(outp + obase + (size_t)(sbase + s) * 64 + c16 + 8) = r1;
    }
    asm volatile("s_waitcnt lgkmcnt(0)" ::: "memory");  // reads done, reuse Lw
  }

  // ---- V: accV lane holds (e = n*16+lc, s = mi*16+kq*4 + r) ----
#pragma unroll
  for (int n = 0; n < 4; ++n) {
    const float bvv = bv[h * 64 + n * 16 + lc];
#pragma unroll
    for (int mi = 0; mi < 2; ++mi) {
      const floatx4 v = accV[mi][n];
      *(uint2*)(&Lw[(n * 16 + lc) * 40 + mi * 16 + kq * 4]) =
          make_uint2(pkbf(v[0] + bvv, v[1] + bvv),
                     pkbf(v[2] + bvv, v[3] + bvv));
    }
  }
  asm volatile("s_waitcnt lgkmcnt(0)" ::: "memory");
  {
    const int erow = lane >> 2, s8 = (lane & 3) * 8;
#pragma unroll
    for (int it = 0; it < 4; ++it) {
      const int e = it * 16 + erow;
      const uint4 r0 = *(const uint4*)(&Lw[e * 40 + s8]);
      *(uint4*)(vt + obase + (size_t)e * S_ + sbase + s8) = r0;
    }
  }
}

// ------- flash attention: 8 waves x 16 q, K/V LDS-staged + XOR-swizzled ----
// (r3/r5 structure, unchanged)
__global__ __launch_bounds__(512) void attn_mfma(
    const ushort_t* __restrict__ qb, const ushort_t* __restrict__ kb,
    const ushort_t* __restrict__ vt, const float* __restrict__ x,
    float* __restrict__ out1) {
  const int bh = blockIdx.x;
  const int tid = threadIdx.x;
  const int wave = tid >> 6, lane = tid & 63;  // wave 0..7
  const int lc = lane & 15, kq = lane >> 4;
  const int q0 = blockIdx.y * 128 + wave * 16;

  __shared__ __align__(16) ushort_t smem[8192 + 8 * 16 * 72];  // 34816 B
  ushort_t* Ks = smem;                       // [key][d], chunk-swizzled
  ushort_t* Vs = smem + 4096;                // [d][s],  chunk-swizzled
  ushort_t* Pp = smem + 8192 + wave * (16 * 72);

  const ushort_t* qp = qb + (size_t)bh * (S_ * 64);
  const ushort_t* kp = kb + (size_t)bh * (S_ * 64);
  const ushort_t* vp = vt + (size_t)bh * (S_ * 64);

  short8 qf[2];
#pragma unroll
  for (int kc = 0; kc < 2; ++kc)
    qf[kc] = *(const short8*)(qp + (size_t)(q0 + lc) * 64 + kc * 32 + kq * 8);

  const int srow = tid >> 3;                             // 0..63
  const int sgc = ((tid & 7) ^ (srow & 7)) * 8;          // global col (elems)
  const int slds = srow * 64 + (tid & 7) * 8;            // LDS offset (elems)
  const int swz = lc & 7;                                // frag-read swizzle

  float l_r = 0.0f;
  floatx4 oacc[4] = {};  // [d-tile]

  for (int kt = 0; kt < 16; ++kt) {
    __builtin_amdgcn_global_load_lds(
        (const __attribute__((address_space(1))) unsigned int*)
            (kp + (size_t)(kt * 64 + srow) * 64 + sgc),
        (__attribute__((address_space(3))) unsigned int*)(Ks + slds), 16, 0, 0);
    __builtin_amdgcn_global_load_lds(
        (const __attribute__((address_space(1))) unsigned int*)
            (vp + (size_t)srow * S_ + kt * 64 + sgc),
        (__attribute__((address_space(3))) unsigned int*)(Vs + slds), 16, 0, 0);
    __syncthreads();

    // ---- QK: S^T tile, 16 q-rows per wave ----
    floatx4 sacc[4] = {};
#pragma unroll
    for (int mi = 0; mi < 4; ++mi) {
      const int row = (mi * 16 + lc) * 64;
#pragma unroll
      for (int kc = 0; kc < 2; ++kc) {
        const short8 kf =
            *(const short8*)(Ks + row + ((kc * 4 + kq) ^ swz) * 8);
        sacc[mi] = __builtin_amdgcn_mfma_f32_16x16x32_bf16(
            kf, qf[kc], sacc[mi], 0, 0, 0);
      }
    }

    // ---- softmax numerator (no max subtraction) ----
    float pr[4][4];
    float sm = 0.f;
#pragma unroll
    for (int mi = 0; mi < 4; ++mi)
#pragma unroll
      for (int r = 0; r < 4; ++r) {
        pr[mi][r] = exp2f(sacc[mi][r]);
        sm += pr[mi][r];
      }
    l_r += sm;  // per-lane partial; reduced at epilogue
#pragma unroll
    for (int mi = 0; mi < 4; ++mi) {
      const unsigned int p01 = pkbf(pr[mi][0], pr[mi][1]);
      const unsigned int p23 = pkbf(pr[mi][2], pr[mi][3]);
      *(uint2*)(&Pp[lc * 72 + mi * 16 + kq * 4]) = make_uint2(p01, p23);
    }
    asm volatile("s_waitcnt lgkmcnt(0)" ::: "memory");

    // ---- PV: O^T += V^T * P^T ----
    short8 pf[2];
#pragma unroll
    for (int kc = 0; kc < 2; ++kc)
      pf[kc] = *(const short8*)(&Pp[lc * 72 + kc * 32 + kq * 8]);
#pragma unroll
    for (int mi = 0; mi < 4; ++mi) {
      const int row = (mi * 16 + lc) * 64;
#pragma unroll
      for (int kc = 0; kc < 2; ++kc) {
        const short8 vf =
            *(const short8*)(Vs + row + ((kc * 4 + kq) ^ swz) * 8);
        oacc[mi] = __builtin_amdgcn_mfma_f32_16x16x32_bf16(
            vf, pf[kc], oacc[mi], 0, 0, 0);
      }
    }
    __syncthreads();  // Ks/Vs/Pp reads done before next stage overwrites
  }

  // ---- epilogue: finalize l, O^T -> LDS -> dense 128-B stores + resid ----
  const int b = bh / H_, h = bh % H_;
  float lt = l_r;
  lt += __shfl_xor(lt, 16);
  lt += __shfl_xor(lt, 32);
  const float inv = 1.0f / lt;
  float* Ow = (float*)smem + wave * 1088;
#pragma unroll
  for (int mi = 0; mi < 4; ++mi) {
    floatx4 ov = oacc[mi];
    ov[0] *= inv; ov[1] *= inv; ov[2] *= inv; ov[3] *= inv;
    *(floatx4*)(&Ow[lc * 68 + mi * 16 + kq * 4]) = ov;
  }
  asm volatile("s_waitcnt lgkmcnt(0)" ::: "memory");
  const int row = (lane >> 3) & 7, c8 = (lane & 7) * 4;
#pragma unroll
  for (int rg = 0; rg < 2; ++rg) {
    const int qq = rg * 8 + row;
    const size_t gbase =
        ((size_t)(b * S_) + q0 + qq) * D_ + h * 64 + c8;
#pragma unroll
    for (int j = 0; j < 2; ++j) {
      const float4 ov = *(const float4*)(&Ow[qq * 68 + j * 32 + c8]);
      const float4 xv = *(const float4*)(x + gbase + j * 32);
      *(float4*)(out1 + gbase + j * 32) =
          make_float4(ov.x + xv.x, ov.y + xv.y, ov.z + xv.z, ov.w + xv.w);
    }
  }
}

// ======== pipelined bf16 MFMA GEMM: BK=64, LDS dbuf, counted vmcnt ========
// Split-MFMA schedule (this round's change): the K-step's MFMAs are split
// around the barrier pair so neither half sits behind the full lgkm drain:
//   reads(ks0,ks1) -> MFMA(ks0)   [compiler-counted lgkmcnt covers ks0 only;
//                                   ks1 reads still in flight]
//   lgkm(0) -> bar#1              [all reads drained -> buffer free]
//   stage(t+2) -> vmcnt(LPT) -> bar#2   [tile t+1 resident]
//   MFMA(ks1)                     [register-only; overlaps other waves'
//                                   next-tile ds_read issue]
// acc order ks0->ks1 unchanged -> bit-identical results.
template <int BM, int BN, int N, int K, bool GELU, bool RESID, bool OUT_BF16,
          bool XCDMAP>
__global__ __launch_bounds__(512, 4) void gemm_pipe(
    const ushort_t* __restrict__ A, const ushort_t* __restrict__ Bt,
    const float* __restrict__ resid, void* __restrict__ Cout) {
  constexpr int MI = BM / 32;             // m-frags per wave
  constexpr int NJ = BN / 64;             // n-frags per wave
  constexpr int LPT = BM / 64 + BN / 64;  // gload_lds per thread per K-tile
  constexpr int NT = K / 64;

  int mb, nb;
  if constexpr (XCDMAP) {
    const int lin = blockIdx.x;
    const int xcd = lin & 7, slot = lin >> 3;
    const int mbg = slot / (N / 128), nbi = slot - mbg * (N / 128);
    mb = (xcd * 16 + mbg) * 64;
    nb = nbi * 128;
  } else {
    nb = blockIdx.x * BN;
    mb = blockIdx.y * BM;
  }

  const int tid = threadIdx.x;
  const int wave = tid >> 6, lane = tid & 63;  // wave 0..7
  const int wm = (wave >> 2) * (BM / 2), wn = (wave & 3) * (BN / 4);

  __shared__ __align__(16) ushort_t Asp[2][BM * 64];
  __shared__ __align__(16) ushort_t Bsp[2][BN * 64];

  // staging geometry: 64 rows x 8 chunks of 16B per issue group
  const int sr = tid >> 3;                      // 0..63
  const int sc8 = (tid & 7) * 8;                // LDS chunk (lane-linear dest)
  const int sgx = ((tid & 7) ^ (sr & 7)) * 8;   // pre-swizzled global chunk

  auto stage = [&](int t, int buf) {
    const int kb = t * 64;
#pragma unroll
    for (int j = 0; j < BM / 64; ++j) {
      const int row = j * 64 + sr;
      __builtin_amdgcn_global_load_lds(
          (const __attribute__((address_space(1))) unsigned int*)
              (A + (size_t)(mb + row) * K + kb + sgx),
          (__attribute__((address_space(3))) unsigned int*)
              (&Asp[buf][row * 64 + sc8]), 16, 0, 0);
    }
#pragma unroll
    for (int j = 0; j < BN / 64; ++j) {
      const int row = j * 64 + sr;
      __builtin_amdgcn_global_load_lds(
          (const __attribute__((address_space(1))) unsigned int*)
              (Bt + (size_t)(nb + row) * K + kb + sgx),
          (__attribute__((address_space(3))) unsigned int*)
              (&Bsp[buf][row * 64 + sc8]), 16, 0, 0);
    }
  };

  // prologue: tiles 0 and 1 in flight; wait for tile 0 only
  stage(0, 0);
  stage(1, 1);
  wait_vmcnt<LPT>();
  __builtin_amdgcn_s_barrier();
  __builtin_amdgcn_sched_barrier(0);

  const int lc = lane & 15, kq = lane >> 4, swz = lc & 7;
  floatx4 acc[MI][NJ] = {};

#pragma unroll 1
  for (int t = 0; t < NT; ++t) {
    const int cur = t & 1;
    short8 af[MI][2], bfr[NJ][2];
#pragma unroll
    for (int ks = 0; ks < 2; ++ks) {
#pragma unroll
      for (int i = 0; i < MI; ++i)
        af[i][ks] = *(const short8*)(&Asp[cur][(wm + i * 16 + lc) * 64 +
                                               ((ks * 4 + kq) ^ swz) * 8]);
#pragma unroll
      for (int j = 0; j < NJ; ++j)
        bfr[j][ks] = *(const short8*)(&Bsp[cur][(wn + j * 16 + lc) * 64 +
                                                ((ks * 4 + kq) ^ swz) * 8]);
    }
    // MFMA half 1 (ks=0): compiler inserts a counted lgkmcnt covering only
    // the ks0 reads, so these overlap the ks1 reads still in flight.
    __builtin_amdgcn_s_setprio(1);
#pragma unroll
    for (int i = 0; i < MI; ++i)
#pragma unroll
      for (int j = 0; j < NJ; ++j)
        acc[i][j] = __builtin_amdgcn_mfma_f32_16x16x32_bf16(
            af[i][0], bfr[j][0], acc[i][j], 0, 0, 0);
    __builtin_amdgcn_s_setprio(0);
    asm volatile("s_waitcnt lgkmcnt(0)" ::: "memory");
    __builtin_amdgcn_sched_barrier(0);
    __builtin_amdgcn_s_barrier();  // #1: all waves' frag reads complete
    __builtin_amdgcn_sched_barrier(0);
    if (t + 2 < NT) stage(t + 2, cur);  // overwrite just-freed buffer
    __builtin_amdgcn_sched_barrier(0);
    if (t + 2 < NT)
      wait_vmcnt<LPT>();  // tile t+1 landed; t+2's LPT stay in flight
    else if (t + 1 < NT)
      wait_vmcnt<0>();    // tail: nothing behind tile t+1
    if (t + 1 < NT) {
      __builtin_amdgcn_s_barrier();  // #2: tile t+1 resident on every wave
      __builtin_amdgcn_sched_barrier(0);
    }
    // MFMA half 2 (ks=1): register-only; overlaps other waves' next-tile
    // ds_read issue after bar#2.
    __builtin_amdgcn_s_setprio(1);
#pragma unroll
    for (int i = 0; i < MI; ++i)
#pragma unroll
      for (int j = 0; j < NJ; ++j)
        acc[i][j] = __builtin_amdgcn_mfma_f32_16x16x32_bf16(
            af[i][1], bfr[j][1], acc[i][j], 0, 0, 0);
    __builtin_amdgcn_s_setprio(0);
  }

  const int lcol = lane & 15, lr4 = (lane >> 4) * 4;
#pragma unroll
  for (int i = 0; i < MI; ++i)
#pragma unroll
    for (int r = 0; r < 4; ++r) {
      const int m = mb + wm + i * 16 + lr4 + r;
#pragma unroll
      for (int j = 0; j < NJ; ++j) {
        const int col = nb + wn + j * 16 + lcol;
        float vv = acc[i][j][r];
        if (GELU) vv = gelu_f(vv);
        if (RESID) vv += resid[(size_t)m * N + col];
        if (OUT_BF16)
          ((ushort_t*)Cout)[(size_t)m * N + col] = f2bf(vv);
        else
          ((float*)Cout)[(size_t)m * N + col] = vv;
      }
    }
}

extern "C" void kernel_launch(void* const* d_in, const int* in_sizes, int n_in,
                              void* d_out, int out_size, void* d_ws, size_t ws_size,
                              hipStream_t stream) {
  (void)in_sizes; (void)n_in; (void)out_size; (void)ws_size;
  const float* x     = (const float*)d_in[0];
  const float* ln1_g = (const float*)d_in[1];
  const float* ln1_b = (const float*)d_in[2];
  const float* Wq    = (const float*)d_in[3];
  const float* bq    = (const float*)d_in[4];
  const float* Wk    = (const float*)d_in[5];
  const float* bk    = (const float*)d_in[6];
  const float* Wv    = (const float*)d_in[7];
  const float* bv    = (const float*)d_in[8];
  const float* ln2_g = (const float*)d_in[9];
  const float* ln2_b = (const float*)d_in[10];
  const float* W1    = (const float*)d_in[11];
  const float* W2    = (const float*)d_in[12];
  float* out = (float*)d_out;

  const size_t n = (size_t)B_ * S_ * D_;  // 6,291,456
  ushort_t* u = (ushort_t*)d_ws;
  ushort_t* xbf  = u;                 // LN1 out bf16
  ushort_t* qb   = xbf + n;           // [96][1024][64]
  ushort_t* kb   = qb + n;
  ushort_t* vt   = kb + n;            // [96][64][1024]  (written by qkv)
  ushort_t* xbf2 = vt + n;            // LN2 out bf16
  ushort_t* act  = xbf2 + n;          // 8192 x 3072
  ushort_t* Wt1  = act + (size_t)8192 * 3072;
  ushort_t* Wt2  = Wt1 + (size_t)3072 * 768;
  ushort_t* Wqt  = Wt2 + (size_t)768 * 3072;
  ushort_t* Wkt  = Wqt + H_ * 4096;
  ushort_t* Wvt  = Wkt + H_ * 4096;
  float* out1 = (float*)(Wvt + H_ * 4096);  // x + attn (fp32), n floats

  prep_weights<<<dim3(4644), dim3(256), 0, stream>>>(
      W1, Wt1, W2, Wt2, Wq, Wk, Wv, Wqt, Wkt, Wvt);
  ln_bf16<<<dim3(2048), dim3(256), 0, stream>>>(x, ln1_g, ln1_b, xbf);
  qkv_mfma<<<dim3(64, 12), dim3(256), 0, stream>>>(xbf, Wqt, Wkt, Wvt,
                                                   bq, bk, bv, qb, kb, vt);
  attn_mfma<<<dim3(96, 8), dim3(512), 0, stream>>>(qb, kb, vt, x, out1);
  ln_bf16<<<dim3(2048), dim3(256), 0, stream>>>(out1, ln2_g, ln2_b, xbf2);
  // FFN GEMM1: 8192x3072x768, GELU, bf16 out (128x128, 8 waves, 2D grid)
  gemm_pipe<128, 128, 3072, 768, true, false, true, false>
      <<<dim3(24, 64), dim3(512), 0, stream>>>(xbf2, Wt1, nullptr, act);
  // FFN GEMM2: 8192x768x3072, +resid, fp32 out (64x128, 8 waves, XCD-grouped)
  gemm_pipe<64, 128, 768, 3072, false, true, false, true>
      <<<dim3(768), dim3(512), 0, stream>>>(act, Wt2, out1, out);
}